// Round 1
// baseline (674.645 us; speedup 1.0000x reference)
//
#include <hip/hip_runtime.h>
#include <math.h>

// Problem: B=64, S=2048, H=1024. Single-query attention + concat.
// out[b, 0:H]    = h_n[b]
// out[b, H:2H]   = softmax_s(h_n[b]·enc[b,s,:]) @ enc[b,:,:]
//
// Memory-bound: enc is 536 MB; single-pass online softmax reads it once.

#define BB 64
#define SS 2048
#define HH 1024
#define NCHUNK 16              // S-chunks per batch -> 64*16 = 1024 blocks
#define SCHUNK (SS / NCHUNK)   // 128 rows per block
#define NWAVE 4                // 256 threads

// ws layout:
//   [0 .. B*NCHUNK*H)                 : partial ctx accumulators (float), 4.19 MB
//   [B*NCHUNK*H .. +B*NCHUNK*2)      : (m, l) pairs per partial
#define WS_ML_OFF ((size_t)BB * NCHUNK * HH)

__global__ __launch_bounds__(256) void attn_partial_kernel(
    const float* __restrict__ enc, const float* __restrict__ hn,
    float* __restrict__ ws)
{
    const int blk   = blockIdx.x;          // b * NCHUNK + chunk
    const int b     = blk / NCHUNK;
    const int chunk = blk % NCHUNK;
    const int tid   = threadIdx.x;
    const int wave  = tid >> 6;
    const int lane  = tid & 63;

    // Preload this lane's 16 h_n elements: h = j*256 + lane*4 + c
    const float4* hn4 = (const float4*)(hn + (size_t)b * HH);
    float4 h4[4];
#pragma unroll
    for (int j = 0; j < 4; ++j) h4[j] = hn4[j * 64 + lane];

    const float4* enc4 = (const float4*)(enc + (size_t)b * SS * HH);

    float m = -INFINITY;
    float l = 0.0f;
    float4 acc[4];
#pragma unroll
    for (int j = 0; j < 4; ++j) acc[j] = make_float4(0.f, 0.f, 0.f, 0.f);

    const int s0 = chunk * SCHUNK;
    for (int s = s0 + wave; s < s0 + SCHUNK; s += NWAVE) {
        const float4* row = enc4 + (size_t)s * (HH / 4);
        float4 e[4];
#pragma unroll
        for (int j = 0; j < 4; ++j) e[j] = row[j * 64 + lane];

        float d = 0.0f;
#pragma unroll
        for (int j = 0; j < 4; ++j) {
            d += e[j].x * h4[j].x + e[j].y * h4[j].y
               + e[j].z * h4[j].z + e[j].w * h4[j].w;
        }
        // wave-64 butterfly reduce
#pragma unroll
        for (int off = 32; off > 0; off >>= 1)
            d += __shfl_xor(d, off, 64);

        // online softmax update
        const float m_new = fmaxf(m, d);
        const float scale = __expf(m - m_new);   // first iter: exp(-inf)=0
        const float p     = __expf(d - m_new);
        l = l * scale + p;
#pragma unroll
        for (int j = 0; j < 4; ++j) {
            acc[j].x = acc[j].x * scale + p * e[j].x;
            acc[j].y = acc[j].y * scale + p * e[j].y;
            acc[j].z = acc[j].z * scale + p * e[j].z;
            acc[j].w = acc[j].w * scale + p * e[j].w;
        }
        m = m_new;
    }

    // ---- combine 4 wave-partials within the block via LDS ----
    __shared__ float s_m[NWAVE];
    __shared__ float s_l[NWAVE];
    __shared__ float s_acc[NWAVE][HH];     // 16 KB

#pragma unroll
    for (int j = 0; j < 4; ++j)
        ((float4*)s_acc[wave])[j * 64 + lane] = acc[j];
    if (lane == 0) { s_m[wave] = m; s_l[wave] = l; }
    __syncthreads();

    float M = fmaxf(fmaxf(s_m[0], s_m[1]), fmaxf(s_m[2], s_m[3]));
    float sc[NWAVE];
    float L = 0.0f;
#pragma unroll
    for (int w = 0; w < NWAVE; ++w) {
        sc[w] = __expf(s_m[w] - M);
        L += s_l[w] * sc[w];
    }

    // each thread finalizes one float4 slot (tid covers 256 slots = 1024 floats)
    float4 ctx = make_float4(0.f, 0.f, 0.f, 0.f);
#pragma unroll
    for (int w = 0; w < NWAVE; ++w) {
        float4 a = ((const float4*)s_acc[w])[tid];
        ctx.x += sc[w] * a.x;  ctx.y += sc[w] * a.y;
        ctx.z += sc[w] * a.z;  ctx.w += sc[w] * a.w;
    }
    ((float4*)(ws + (size_t)blk * HH))[tid] = ctx;
    if (tid == 0) {
        ws[WS_ML_OFF + (size_t)blk * 2 + 0] = M;
        ws[WS_ML_OFF + (size_t)blk * 2 + 1] = L;
    }
}

__global__ __launch_bounds__(256) void attn_final_kernel(
    const float* __restrict__ hn, const float* __restrict__ ws,
    float* __restrict__ out)
{
    const int b   = blockIdx.x;
    const int tid = threadIdx.x;
    const float* ml = ws + WS_ML_OFF + (size_t)b * NCHUNK * 2;

    float M = -INFINITY;
#pragma unroll
    for (int c = 0; c < NCHUNK; ++c) M = fmaxf(M, ml[c * 2]);

    float sc[NCHUNK];
    float T = 0.0f;
#pragma unroll
    for (int c = 0; c < NCHUNK; ++c) {
        sc[c] = __expf(ml[c * 2] - M);
        T += sc[c] * ml[c * 2 + 1];
    }
    const float invT = 1.0f / T;

    float4 ctx = make_float4(0.f, 0.f, 0.f, 0.f);
#pragma unroll
    for (int c = 0; c < NCHUNK; ++c) {
        float4 a = ((const float4*)(ws + (size_t)(b * NCHUNK + c) * HH))[tid];
        ctx.x += sc[c] * a.x;  ctx.y += sc[c] * a.y;
        ctx.z += sc[c] * a.z;  ctx.w += sc[c] * a.w;
    }
    ctx.x *= invT; ctx.y *= invT; ctx.z *= invT; ctx.w *= invT;

    const float4 dec = ((const float4*)(hn + (size_t)b * HH))[tid];
    float4* o = (float4*)(out + (size_t)b * 2 * HH);
    o[tid]                = dec;   // dec_output half
    o[tid + (HH / 4)]     = ctx;   // context half
}

extern "C" void kernel_launch(void* const* d_in, const int* in_sizes, int n_in,
                              void* d_out, int out_size, void* d_ws, size_t ws_size,
                              hipStream_t stream) {
    const float* enc = (const float*)d_in[0];   // (B, S, H) fp32
    const float* hn  = (const float*)d_in[1];   // (B, H) fp32
    float* out = (float*)d_out;                 // (B, 1, 2H) fp32
    float* ws  = (float*)d_ws;

    attn_partial_kernel<<<dim3(BB * NCHUNK), dim3(256), 0, stream>>>(enc, hn, ws);
    attn_final_kernel<<<dim3(BB), dim3(256), 0, stream>>>(hn, ws, out);
}